// Round 4
// baseline (286.880 us; speedup 1.0000x reference)
//
#include <hip/hip_runtime.h>
#include <cstdint>
#include <cstddef>

#define T_SEQ 2048
#define B_SZ  2
#define EMB   2048
#define NH    16
#define NKV   4
#define HD    128
#define KVD   512
#define QKVN  3072
#define MROWS (B_SZ*T_SEQ)

typedef __bf16 bf16x8 __attribute__((ext_vector_type(8)));
typedef float  f32x4  __attribute__((ext_vector_type(4)));
typedef short  s16x8  __attribute__((ext_vector_type(8)));
typedef unsigned short u16;

__device__ __forceinline__ u16 f2b(float f) {
  uint32_t u = __builtin_bit_cast(uint32_t, f);
  u += 0x7fffu + ((u >> 16) & 1u);      // RNE
  return (u16)(u >> 16);
}
__device__ __forceinline__ float b2f(u16 h) {
  return __builtin_bit_cast(float, (uint32_t)h << 16);
}
__device__ __forceinline__ bf16x8 ld_bf8(const u16* p) {
  return __builtin_bit_cast(bf16x8, *(const s16x8*)p);
}
__device__ __forceinline__ void glds16(const void* g, void* l) {
  __builtin_amdgcn_global_load_lds((const __attribute__((address_space(1))) void*)g,
                                   (__attribute__((address_space(3))) void*)l, 16, 0, 0);
}
template<int N> __device__ __forceinline__ void waitv() {
  if constexpr (N == 0) asm volatile("s_waitcnt vmcnt(0)" ::: "memory");
  else if constexpr (N == 2) asm volatile("s_waitcnt vmcnt(2)" ::: "memory");
  else if constexpr (N == 3) asm volatile("s_waitcnt vmcnt(3)" ::: "memory");
  __builtin_amdgcn_sched_barrier(0);
}

// ---------------- fp32 -> bf16 elementwise ----------------
__global__ void cvt_x_kernel(const float4* __restrict__ x, ushort4* __restrict__ xb, int n4) {
  int i = blockIdx.x*blockDim.x + threadIdx.x;
  if (i >= n4) return;
  float4 v = x[i];
  ushort4 o;
  o.x = f2b(v.x); o.y = f2b(v.y); o.z = f2b(v.z); o.w = f2b(v.w);
  xb[i] = o;
}

// ---------------- fp32 (R x C) -> bf16 transposed (C x R) ----------------
__global__ void transpose_w_kernel(const float* __restrict__ in, u16* __restrict__ out,
                                   int R, int C) {
  __shared__ float tile[32][33];
  int c0 = blockIdx.x*32, r0 = blockIdx.y*32;
  int tx = threadIdx.x, ty = threadIdx.y;
#pragma unroll
  for (int i = 0; i < 32; i += 8)
    tile[ty+i][tx] = in[(size_t)(r0+ty+i)*C + c0+tx];
  __syncthreads();
#pragma unroll
  for (int i = 0; i < 32; i += 8)
    out[(size_t)(c0+ty+i)*R + r0+tx] = f2b(tile[tx][ty+i]);
}

// ---------------- bf16 GEMM, 256xBN tile, 8-phase counted-vmcnt schedule ----
// (unchanged from r2 — verified: 256 blocks = 1/CU for both instantiations)
template<int BN, int WGN, int MF, int NF, int NF1, int SB, int SB1, int VMC, bool BF16_OUT>
__global__ __launch_bounds__(512, 2) void gemm_kernel(const u16* __restrict__ A,
        const u16* __restrict__ Bt, const float* __restrict__ bias,
        void* __restrict__ Cout, int M, int N, int K) {
  constexpr int MF2 = MF/2;
  __shared__ u16 As[2][256*64];
  __shared__ u16 Bs[2][BN*64];
  const int tid = threadIdx.x;
  const int w = tid >> 6, lane = tid & 63;
  const int quad = lane >> 4, lc = lane & 15;
  const int wrow = w / WGN, wcol = w % WGN;
  const int gx = gridDim.x;
  const int lin = blockIdx.y*gx + blockIdx.x;
  const int swz = (lin & 7)*32 + (lin >> 3);
  const int m0 = (swz / gx)*256, n0 = (swz % gx)*BN;

  f32x4 acc[MF][NF] = {};
  bf16x8 af[MF2][2], bfv[NF][2];

  int xoff[2];
#pragma unroll
  for (int ks = 0; ks < 2; ++ks) xoff[ks] = ((ks*4 + quad) ^ (lc & 7))*8;
  const int arow0 = (wrow*MF*16 + lc)*64;
  const int brow0 = (wcol*NF*16 + lc)*64;

  const int srb  = tid >> 3;
  const int spos = (tid & 7) ^ (srb & 7);
  const u16* sAp = A  + (size_t)(m0 + srb)*K + spos*8;
  const u16* sBp = Bt + (size_t)(n0 + srb)*K + spos*8;

#define STAGE_A(bf_, t_, h_) do { \
    glds16(sAp + (size_t)((h_)*2  )*64*K + (size_t)(t_)*64, &As[bf_][((h_)*2  )*4096 + w*512]); \
    glds16(sAp + (size_t)((h_)*2+1)*64*K + (size_t)(t_)*64, &As[bf_][((h_)*2+1)*4096 + w*512]); \
  } while (0)
#define STAGE_B(bf_, t_, p_) do { \
    _Pragma("unroll") for (int r = (p_) ? SB1 : 0; r < ((p_) ? SB : SB1); ++r) \
      glds16(sBp + (size_t)r*64*K + (size_t)(t_)*64, &Bs[bf_][r*4096 + w*512]); \
  } while (0)
#define LDAH(S_, h_) do { _Pragma("unroll") for (int i = 0; i < MF2; ++i) { \
    af[i][0] = ld_bf8((S_) + arow0 + ((h_)*MF2 + i)*1024 + xoff[0]); \
    af[i][1] = ld_bf8((S_) + arow0 + ((h_)*MF2 + i)*1024 + xoff[1]); } } while (0)
#define LDBG(S_, g_) do { _Pragma("unroll") for (int j = (g_) ? NF1 : 0; j < ((g_) ? NF : NF1); ++j) { \
    bfv[j][0] = ld_bf8((S_) + brow0 + j*1024 + xoff[0]); \
    bfv[j][1] = ld_bf8((S_) + brow0 + j*1024 + xoff[1]); } } while (0)
#define CL(h_, g_) do { _Pragma("unroll") for (int ks = 0; ks < 2; ++ks) \
    _Pragma("unroll") for (int i = 0; i < MF2; ++i) \
    _Pragma("unroll") for (int j = (g_) ? NF1 : 0; j < ((g_) ? NF : NF1); ++j) \
      acc[(h_)*MF2+i][j] = __builtin_amdgcn_mfma_f32_16x16x32_bf16( \
          af[i][ks], bfv[j][ks], acc[(h_)*MF2+i][j], 0, 0, 0); } while (0)
#define BARX()  __builtin_amdgcn_s_barrier()
#define SCHB()  __builtin_amdgcn_sched_barrier(0)
#define MFMAPH(h_, g_) do { BARX(); \
    asm volatile("s_waitcnt lgkmcnt(0)" ::: "memory"); SCHB(); \
    __builtin_amdgcn_s_setprio(1); CL(h_, g_); __builtin_amdgcn_s_setprio(0); \
  } while (0)

  const int NT = K >> 6;
  STAGE_B(0, 0, 0); STAGE_B(0, 0, 1);
  STAGE_A(0, 0, 0); STAGE_A(0, 0, 1);
  STAGE_B(1, 1, 0); STAGE_B(1, 1, 1);
  waitv<VMC>();
  BARX(); SCHB();

  for (int t0 = 0; t0 < NT-2; t0 += 2) {
    const u16 *a0 = As[0], *b0 = Bs[0], *a1 = As[1], *b1 = Bs[1];
    LDAH(a0, 0); LDBG(b0, 0); STAGE_A(1, t0+1, 0);
    MFMAPH(0, 0); BARX();
    LDBG(b0, 1); STAGE_A(1, t0+1, 1);
    MFMAPH(0, 1); BARX();
    LDAH(a0, 1); STAGE_B(0, t0+2, 0);
    MFMAPH(1, 0); BARX();
    STAGE_B(0, t0+2, 1);
    MFMAPH(1, 1);
    waitv<VMC>();
    BARX(); SCHB();
    LDAH(a1, 0); LDBG(b1, 0); STAGE_A(0, t0+2, 0);
    MFMAPH(0, 0); BARX();
    LDBG(b1, 1); STAGE_A(0, t0+2, 1);
    MFMAPH(0, 1); BARX();
    LDAH(a1, 1); STAGE_B(1, t0+3, 0);
    MFMAPH(1, 0); BARX();
    STAGE_B(1, t0+3, 1);
    MFMAPH(1, 1);
    waitv<VMC>();
    BARX(); SCHB();
  }
  {
    const u16 *a0 = As[0], *b0 = Bs[0], *a1 = As[1], *b1 = Bs[1];
    LDAH(a0, 0); LDBG(b0, 0); STAGE_A(1, NT-1, 0);
    MFMAPH(0, 0); BARX();
    LDBG(b0, 1); STAGE_A(1, NT-1, 1);
    MFMAPH(0, 1); BARX();
    LDAH(a0, 1);
    MFMAPH(1, 0); BARX();
    MFMAPH(1, 1);
    waitv<0>();
    BARX(); SCHB();
    LDAH(a1, 0); LDBG(b1, 0);
    MFMAPH(0, 0); BARX();
    LDBG(b1, 1);
    MFMAPH(0, 1); BARX();
    LDAH(a1, 1);
    MFMAPH(1, 0); BARX();
    MFMAPH(1, 1);
  }

#undef STAGE_A
#undef STAGE_B
#undef LDAH
#undef LDBG
#undef CL
#undef BARX
#undef SCHB
#undef MFMAPH

#pragma unroll
  for (int j = 0; j < NF; ++j) {
    int col = n0 + wcol*NF*16 + j*16 + lc;
    float bv = BF16_OUT ? bias[col] : 0.0f;
#pragma unroll
    for (int i = 0; i < MF; ++i) {
      int rowb = m0 + wrow*MF*16 + i*16 + quad*4;
#pragma unroll
      for (int r = 0; r < 4; ++r) {
        float v = acc[i][j][r] + bv;
        if (BF16_OUT) ((u16*)Cout)[(size_t)(rowb+r)*N + col] = f2b(v);
        else          ((float*)Cout)[(size_t)(rowb+r)*N + col] = v;
      }
    }
  }
}

// ---------------- RoPE on K and V (reference ropes V too, not Q) ----------------
__global__ void rope_kernel(const u16* __restrict__ qkv, const float* __restrict__ fc,
                            const float* __restrict__ fs, u16* __restrict__ kout,
                            u16* __restrict__ vout) {
  int tid = threadIdx.x;
  int row = blockIdx.x;             // b*T + t
  int i = tid & 63, kv = tid >> 6;  // pair index, kv head
  int t = row & (T_SEQ-1);
  const u16* p = qkv + (size_t)row*QKVN + EMB + kv*HD + 2*i;
  float ka = b2f(p[0]),   kb = b2f(p[1]);
  float va = b2f(p[KVD]), vb = b2f(p[KVD+1]);
  float c = fc[t*64+i], s = fs[t*64+i];
  size_t ob = (size_t)row*KVD + kv*HD + 2*i;
  kout[ob]   = f2b(ka*c - kb*s);
  kout[ob+1] = f2b(ka*s + kb*c);
  vout[ob]   = f2b(va*c - vb*s);
  vout[ob+1] = f2b(va*s + vb*c);
}

// ---------------- V (b,t,kv,d) -> Vt (b,kv,d,t) ----------------
__global__ void transpose_v_kernel(const u16* __restrict__ vb, u16* __restrict__ vtb) {
  __shared__ u16 tile[32][33];
  int bkv = blockIdx.z;
  int b = bkv >> 2, kv = bkv & 3;
  int d0 = blockIdx.y*32, t0 = blockIdx.x*32;
  int tx = threadIdx.x, ty = threadIdx.y;
#pragma unroll
  for (int i = 0; i < 32; i += 8)
    tile[ty+i][tx] = vb[(size_t)(b*T_SEQ + t0+ty+i)*KVD + kv*HD + d0 + tx];
  __syncthreads();
#pragma unroll
  for (int i = 0; i < 32; i += 8)
    vtb[(size_t)(bkv*HD + d0+ty+i)*T_SEQ + t0 + tx] = tile[tx][ty+i];
}

// ---------------- flash attention v6: 8-wave blocks, 32 queries/block -------
// One 512-thread block per (b, kv-group, 32-query tile). 8 waves = 4 heads x
// 2 adjacent 16-query sub-tiles sharing the staged K/V (8x GQA+q reuse vs v5's
// 4x). v6 changes vs v5 (counters: MfmaUtil 21, VALUBusy 30, Occ 20 ->
// latency/occupancy-bound, not VALU):
//  - waves/CU 6.5 -> 16 (2 blocks x 8 waves): 4 streams/SIMD feed the MFMA
//    pipe through each wave's serial QK->softmax->PV chain.
//  - staging instrs per query halved (4 glds16/thread/tile for 32 queries).
//  - Ps pitch 72 -> 64 with chunk-XOR swizzle (write cc^=row&7, read same):
//    LDS = 2*16K(Ks) + 2*16K(Vs) + 16K(Ps) = exactly 80 KB -> 2 blocks/CU.
//  - lower-q waves compute a fully-masked extra tile in ~25% of blocks (~3%
//    waste); masking already zeroes those P entries.
__global__ __launch_bounds__(512, 4) void flash_kernel(const u16* __restrict__ qkv,
    const u16* __restrict__ kb, const u16* __restrict__ vtb, u16* __restrict__ yb) {
  __shared__ u16 Ks[2][64*128];          // 2 x 16 KB
  __shared__ u16 Vs[2][128*64];          // 2 x 16 KB
  __shared__ u16 Ps[8][16*64];           // 8 x 2 KB (chunk-XOR swizzled)
  const int tid = threadIdx.x;
  const int w = tid >> 6, lane = tid & 63;
  const int quad = lane >> 4, lc = lane & 15;
  const int bkv = blockIdx.x & 7;        // XCD-pinned (b,kv)
  const int r_  = blockIdx.x >> 3;       // 0..63
  const int b = bkv >> 2, kv = bkv & 3;
  const int h  = kv*4 + (w & 3);         // head within the group
  const int qt = w >> 2;                 // 0/1: which 16-query sub-tile
  const int qbaseB = (63 - r_)*32;       // heavy q-tiles dispatch first
  const int qbase  = qbaseB + qt*16;

  // Q frags (A-layout) for 16 queries of head h; no RoPE on Q
  bf16x8 qf[4];
  {
    const u16* qp = qkv + (size_t)(b*T_SEQ + qbase + lc)*QKVN + h*HD + quad*8;
#pragma unroll
    for (int ks = 0; ks < 4; ++ks) qf[ks] = ld_bf8(qp + ks*32);
  }

  f32x4 o[8] = {};
  float rs[4] = {0.f, 0.f, 0.f, 0.f};
  const u16* kbase = kb  + (size_t)b*T_SEQ*KVD + kv*HD;
  const u16* vbase = vtb + (size_t)bkv*HD*T_SEQ;
  const int nk = qbaseB + 32;            // block-wide key count (max over waves)
  const int nt = (nk + 63) >> 6;
  const float cs = 0.08838834764831845f * 1.4426950408889634f;  // scale * log2(e)
  u16* pw = Ps[w];

  // staging: 1024 chunks per tile, 512 threads -> 2 chunks each (rr=0,1),
  // chunk ci = rr*512 + w*64 + lane; source-side XOR swizzle per tile layout
  const u16* kptr[2];
  const u16* vptr[2];
#pragma unroll
  for (int rr = 0; rr < 2; ++rr) {
    int ci = rr*512 + w*64 + lane;
    int krow = ci >> 4, kcc = (ci & 15) ^ (krow & 15);
    kptr[rr] = kbase + (size_t)krow*KVD + kcc*8;
    int vrow = ci >> 3, vcc = (ci & 7) ^ (vrow & 7);
    vptr[rr] = vbase + (size_t)vrow*T_SEQ + vcc*8;
  }

  // per-lane swizzled chunk offsets (hoisted out of the K-loop)
  int koff[4], voff[2], poff[2];
#pragma unroll
  for (int ks = 0; ks < 4; ++ks) koff[ks] = lc*128 + (((ks*4 + quad) ^ lc)*8);
#pragma unroll
  for (int ks = 0; ks < 2; ++ks) voff[ks] = lc*64 + (((ks*4 + quad) ^ (lc & 7))*8);
#pragma unroll
  for (int ks = 0; ks < 2; ++ks) poff[ks] = lc*64 + (((ks*4 + quad) ^ (lc & 7))*8);
  // P-write helpers: row = quad*4+r, addr = row*64 + ((nt2*2+(lc>>3))^(row&7))*8 + (lc&7)
  int pwb[4], pwx[4];
#pragma unroll
  for (int r = 0; r < 4; ++r) {
    pwb[r] = (quad*4 + r)*64 + (lc & 7);
    pwx[r] = (quad*4 + r) & 7;
  }
  const int pcc = lc >> 3;

  // prologue: stage tile 0 -> buf 0, publish
#pragma unroll
  for (int rr = 0; rr < 2; ++rr) glds16(kptr[rr], &Ks[0][rr*4096 + w*512]);
#pragma unroll
  for (int rr = 0; rr < 2; ++rr) glds16(vptr[rr], &Vs[0][rr*4096 + w*512]);
  asm volatile("s_waitcnt vmcnt(0)" ::: "memory");
  __builtin_amdgcn_sched_barrier(0);
  __builtin_amdgcn_s_barrier();
  __builtin_amdgcn_sched_barrier(0);

  for (int t = 0; t < nt; ++t) {
    const int cur = t & 1;
    // prefetch tile t+1 into the other buffer (protected by barrier(end t-1))
    if (t + 1 < nt) {
#pragma unroll
      for (int rr = 0; rr < 2; ++rr)
        glds16(kptr[rr] + (size_t)(t+1)*64*KVD, &Ks[cur^1][rr*4096 + w*512]);
#pragma unroll
      for (int rr = 0; rr < 2; ++rr)
        glds16(vptr[rr] + (size_t)(t+1)*64,     &Vs[cur^1][rr*4096 + w*512]);
    }
    const u16* ksb = Ks[cur];
    const u16* vsb = Vs[cur];
    const int k0 = t*64;

    // S = Q K^T : 16 queries x 64 keys
    f32x4 sc[4] = {};
    __builtin_amdgcn_s_setprio(1);
#pragma unroll
    for (int nt2 = 0; nt2 < 4; ++nt2)
#pragma unroll
      for (int ks = 0; ks < 4; ++ks) {
        bf16x8 kf = ld_bf8(ksb + nt2*16*128 + koff[ks]);
        sc[nt2] = __builtin_amdgcn_mfma_f32_16x16x32_bf16(qf[ks], kf, sc[nt2], 0, 0, 0);
      }
    __builtin_amdgcn_s_setprio(0);

    // softmax (m=0): p = exp2(s*cs); mask only on diagonal/partial tiles
    if (k0 + 63 > qbase) {
#pragma unroll
      for (int nt2 = 0; nt2 < 4; ++nt2) {
        int key = k0 + nt2*16 + lc;
        int qrow = qbase + quad*4;
#pragma unroll
        for (int r = 0; r < 4; ++r) {
          float e = __builtin_amdgcn_exp2f(sc[nt2][r]*cs);
          float p = (key <= qrow + r) ? e : 0.0f;
          rs[r] += p;
          pw[pwb[r] + ((nt2*2 + pcc) ^ pwx[r])*8] = f2b(p);
        }
      }
    } else {
#pragma unroll
      for (int nt2 = 0; nt2 < 4; ++nt2)
#pragma unroll
        for (int r = 0; r < 4; ++r) {
          float p = __builtin_amdgcn_exp2f(sc[nt2][r]*cs);
          rs[r] += p;
          pw[pwb[r] + ((nt2*2 + pcc) ^ pwx[r])*8] = f2b(p);
        }
    }

    // P: C-layout -> A-layout via per-wave LDS roundtrip (intra-wave DS in-order)
    bf16x8 pa[2];
#pragma unroll
    for (int ks = 0; ks < 2; ++ks)
      pa[ks] = ld_bf8(pw + poff[ks]);

    // O += P V
    __builtin_amdgcn_s_setprio(1);
#pragma unroll
    for (int j = 0; j < 8; ++j)
#pragma unroll
      for (int ks = 0; ks < 2; ++ks) {
        bf16x8 vf = ld_bf8(vsb + j*16*64 + voff[ks]);
        o[j] = __builtin_amdgcn_mfma_f32_16x16x32_bf16(pa[ks], vf, o[j], 0, 0, 0);
      }
    __builtin_amdgcn_s_setprio(0);

    // publish prefetched tile: own loads drained, then block-wide sync
    asm volatile("s_waitcnt vmcnt(0)" ::: "memory");
    __builtin_amdgcn_sched_barrier(0);
    __builtin_amdgcn_s_barrier();
    __builtin_amdgcn_sched_barrier(0);
  }

  // epilogue: l-reduce over the 16 key-lanes, normalize, store
#pragma unroll
  for (int r = 0; r < 4; ++r) {
    float v = rs[r];
#pragma unroll
    for (int off2 = 8; off2 >= 1; off2 >>= 1)
      v += __shfl_xor(v, off2);
    float inv = 1.0f / v;
    size_t orow = (size_t)(b*T_SEQ + qbase + quad*4 + r)*EMB + h*HD;
#pragma unroll
    for (int j = 0; j < 8; ++j)
      yb[orow + j*16 + lc] = f2b(o[j][r]*inv);
  }
}

extern "C" void kernel_launch(void* const* d_in, const int* in_sizes, int n_in,
                              void* d_out, int out_size, void* d_ws, size_t ws_size,
                              hipStream_t stream) {
  const float* x      = (const float*)d_in[0];
  const float* W_attn = (const float*)d_in[1];
  const float* b_attn = (const float*)d_in[2];
  const float* W_proj = (const float*)d_in[3];
  const float* fc     = (const float*)d_in[4];
  const float* fs     = (const float*)d_in[5];

  u16* ws   = (u16*)d_ws;
  u16* xb   = ws;                          // 8.39M elems  (later aliased by yb)
  u16* WaT  = xb   + (size_t)MROWS*EMB;    // 6.29M        (later aliased by WpT)
  u16* qkv  = WaT  + (size_t)QKVN*EMB;     // 12.58M
  u16* kbuf = qkv  + (size_t)MROWS*QKVN;   // 2.10M
  u16* vb   = kbuf + (size_t)MROWS*KVD;    // 2.10M
  u16* vtb  = vb   + (size_t)MROWS*KVD;    // 2.10M  -> total 67.1 MB
  u16* WpT  = WaT;   // W_attn^T dead after gemm1
  u16* yb   = xb;    // x_bf16 dead after gemm1
  float* out = (float*)d_out;

  cvt_x_kernel<<<(MROWS*EMB/4 + 255)/256, 256, 0, stream>>>(
      (const float4*)x, (ushort4*)xb, MROWS*EMB/4);
  transpose_w_kernel<<<dim3(QKVN/32, EMB/32), dim3(32, 8), 0, stream>>>(
      W_attn, WaT, EMB, QKVN);
  // gemm1: 256x192 tiles -> 16x16 = 256 blocks (1/CU)
  gemm_kernel<192, 4, 8, 3, 2, 3, 2, 3, true>
      <<<dim3(QKVN/192, MROWS/256), 512, 0, stream>>>(
      xb, WaT, b_attn, qkv, MROWS, QKVN, EMB);
  rope_kernel<<<MROWS, 256, 0, stream>>>(qkv, fc, fs, kbuf, vb);
  transpose_v_kernel<<<dim3(T_SEQ/32, HD/32, B_SZ*NKV), dim3(32, 8), 0, stream>>>(vb, vtb);
  transpose_w_kernel<<<dim3(EMB/32, EMB/32), dim3(32, 8), 0, stream>>>(
      W_proj, WpT, EMB, EMB);
  // flash v6: 512 blocks (2/CU), 512 threads = 8 waves = 4 heads x 2 q-tiles
  flash_kernel<<<dim3(B_SZ*NKV*(T_SEQ/32)), 512, 0, stream>>>(qkv, kbuf, vtb, yb);
  // gemm2: 256x128 tiles -> 16x16 = 256 blocks (1/CU)
  gemm_kernel<128, 2, 4, 4, 2, 2, 1, 2, false>
      <<<dim3(EMB/128, MROWS/256), 512, 0, stream>>>(
      yb, WpT, nullptr, out, MROWS, EMB, EMB);
}

// Round 5
// 283.072 us; speedup vs baseline: 1.0135x; 1.0135x over previous
//
#include <hip/hip_runtime.h>
#include <cstdint>
#include <cstddef>

#define T_SEQ 2048
#define B_SZ  2
#define EMB   2048
#define NH    16
#define NKV   4
#define HD    128
#define KVD   512
#define QKVN  3072
#define MROWS (B_SZ*T_SEQ)

typedef __bf16 bf16x8 __attribute__((ext_vector_type(8)));
typedef float  f32x4  __attribute__((ext_vector_type(4)));
typedef short  s16x8  __attribute__((ext_vector_type(8)));
typedef unsigned short u16;

__device__ __forceinline__ u16 f2b(float f) {
  uint32_t u = __builtin_bit_cast(uint32_t, f);
  u += 0x7fffu + ((u >> 16) & 1u);      // RNE
  return (u16)(u >> 16);
}
__device__ __forceinline__ float b2f(u16 h) {
  return __builtin_bit_cast(float, (uint32_t)h << 16);
}
__device__ __forceinline__ bf16x8 ld_bf8(const u16* p) {
  return __builtin_bit_cast(bf16x8, *(const s16x8*)p);
}
__device__ __forceinline__ void glds16(const void* g, void* l) {
  __builtin_amdgcn_global_load_lds((const __attribute__((address_space(1))) void*)g,
                                   (__attribute__((address_space(3))) void*)l, 16, 0, 0);
}
template<int N> __device__ __forceinline__ void waitv() {
  if constexpr (N == 0) asm volatile("s_waitcnt vmcnt(0)" ::: "memory");
  else if constexpr (N == 2) asm volatile("s_waitcnt vmcnt(2)" ::: "memory");
  else if constexpr (N == 3) asm volatile("s_waitcnt vmcnt(3)" ::: "memory");
  __builtin_amdgcn_sched_barrier(0);
}

// ---------------- fp32 -> bf16 elementwise ----------------
__global__ void cvt_x_kernel(const float4* __restrict__ x, ushort4* __restrict__ xb, int n4) {
  int i = blockIdx.x*blockDim.x + threadIdx.x;
  if (i >= n4) return;
  float4 v = x[i];
  ushort4 o;
  o.x = f2b(v.x); o.y = f2b(v.y); o.z = f2b(v.z); o.w = f2b(v.w);
  xb[i] = o;
}

// ---------------- fp32 (R x C) -> bf16 transposed (C x R), vectorized -------
// 64x64 tiles, block (16,16). float4 loads (256B/row-quarter), ushort4 stores
// (128B/row). LDS [64][65] f32: write 2-way, read 2-way bank aliasing (free).
// Replaces the scalar-load/scalar-u16-store version (half-wave 64B stores).
__global__ void transpose_w_kernel(const float* __restrict__ in, u16* __restrict__ out,
                                   int R, int C) {
  __shared__ float tile[64][65];
  int c0 = blockIdx.x*64, r0 = blockIdx.y*64;
  int tx = threadIdx.x, ty = threadIdx.y;   // 16,16
#pragma unroll
  for (int k = 0; k < 4; ++k) {
    int r = ty + k*16;
    float4 v = *(const float4*)&in[(size_t)(r0+r)*C + c0 + tx*4];
    tile[r][tx*4+0] = v.x; tile[r][tx*4+1] = v.y;
    tile[r][tx*4+2] = v.z; tile[r][tx*4+3] = v.w;
  }
  __syncthreads();
#pragma unroll
  for (int k = 0; k < 4; ++k) {
    int c = ty + k*16;                      // output row = original col
    ushort4 o;
    o.x = f2b(tile[tx*4+0][c]);
    o.y = f2b(tile[tx*4+1][c]);
    o.z = f2b(tile[tx*4+2][c]);
    o.w = f2b(tile[tx*4+3][c]);
    *(ushort4*)&out[(size_t)(c0+c)*R + r0 + tx*4] = o;
  }
}

// ---------------- bf16 GEMM, 256xBN tile, 8-phase counted-vmcnt schedule ----
// (unchanged from r2 — verified: 256 blocks = 1/CU for both instantiations)
template<int BN, int WGN, int MF, int NF, int NF1, int SB, int SB1, int VMC, bool BF16_OUT>
__global__ __launch_bounds__(512, 2) void gemm_kernel(const u16* __restrict__ A,
        const u16* __restrict__ Bt, const float* __restrict__ bias,
        void* __restrict__ Cout, int M, int N, int K) {
  constexpr int MF2 = MF/2;
  __shared__ u16 As[2][256*64];
  __shared__ u16 Bs[2][BN*64];
  const int tid = threadIdx.x;
  const int w = tid >> 6, lane = tid & 63;
  const int quad = lane >> 4, lc = lane & 15;
  const int wrow = w / WGN, wcol = w % WGN;
  const int gx = gridDim.x;
  const int lin = blockIdx.y*gx + blockIdx.x;
  const int swz = (lin & 7)*32 + (lin >> 3);
  const int m0 = (swz / gx)*256, n0 = (swz % gx)*BN;

  f32x4 acc[MF][NF] = {};
  bf16x8 af[MF2][2], bfv[NF][2];

  int xoff[2];
#pragma unroll
  for (int ks = 0; ks < 2; ++ks) xoff[ks] = ((ks*4 + quad) ^ (lc & 7))*8;
  const int arow0 = (wrow*MF*16 + lc)*64;
  const int brow0 = (wcol*NF*16 + lc)*64;

  const int srb  = tid >> 3;
  const int spos = (tid & 7) ^ (srb & 7);
  const u16* sAp = A  + (size_t)(m0 + srb)*K + spos*8;
  const u16* sBp = Bt + (size_t)(n0 + srb)*K + spos*8;

#define STAGE_A(bf_, t_, h_) do { \
    glds16(sAp + (size_t)((h_)*2  )*64*K + (size_t)(t_)*64, &As[bf_][((h_)*2  )*4096 + w*512]); \
    glds16(sAp + (size_t)((h_)*2+1)*64*K + (size_t)(t_)*64, &As[bf_][((h_)*2+1)*4096 + w*512]); \
  } while (0)
#define STAGE_B(bf_, t_, p_) do { \
    _Pragma("unroll") for (int r = (p_) ? SB1 : 0; r < ((p_) ? SB : SB1); ++r) \
      glds16(sBp + (size_t)r*64*K + (size_t)(t_)*64, &Bs[bf_][r*4096 + w*512]); \
  } while (0)
#define LDAH(S_, h_) do { _Pragma("unroll") for (int i = 0; i < MF2; ++i) { \
    af[i][0] = ld_bf8((S_) + arow0 + ((h_)*MF2 + i)*1024 + xoff[0]); \
    af[i][1] = ld_bf8((S_) + arow0 + ((h_)*MF2 + i)*1024 + xoff[1]); } } while (0)
#define LDBG(S_, g_) do { _Pragma("unroll") for (int j = (g_) ? NF1 : 0; j < ((g_) ? NF : NF1); ++j) { \
    bfv[j][0] = ld_bf8((S_) + brow0 + j*1024 + xoff[0]); \
    bfv[j][1] = ld_bf8((S_) + brow0 + j*1024 + xoff[1]); } } while (0)
#define CL(h_, g_) do { _Pragma("unroll") for (int ks = 0; ks < 2; ++ks) \
    _Pragma("unroll") for (int i = 0; i < MF2; ++i) \
    _Pragma("unroll") for (int j = (g_) ? NF1 : 0; j < ((g_) ? NF : NF1); ++j) \
      acc[(h_)*MF2+i][j] = __builtin_amdgcn_mfma_f32_16x16x32_bf16( \
          af[i][ks], bfv[j][ks], acc[(h_)*MF2+i][j], 0, 0, 0); } while (0)
#define BARX()  __builtin_amdgcn_s_barrier()
#define SCHB()  __builtin_amdgcn_sched_barrier(0)
#define MFMAPH(h_, g_) do { BARX(); \
    asm volatile("s_waitcnt lgkmcnt(0)" ::: "memory"); SCHB(); \
    __builtin_amdgcn_s_setprio(1); CL(h_, g_); __builtin_amdgcn_s_setprio(0); \
  } while (0)

  const int NT = K >> 6;
  STAGE_B(0, 0, 0); STAGE_B(0, 0, 1);
  STAGE_A(0, 0, 0); STAGE_A(0, 0, 1);
  STAGE_B(1, 1, 0); STAGE_B(1, 1, 1);
  waitv<VMC>();
  BARX(); SCHB();

  for (int t0 = 0; t0 < NT-2; t0 += 2) {
    const u16 *a0 = As[0], *b0 = Bs[0], *a1 = As[1], *b1 = Bs[1];
    LDAH(a0, 0); LDBG(b0, 0); STAGE_A(1, t0+1, 0);
    MFMAPH(0, 0); BARX();
    LDBG(b0, 1); STAGE_A(1, t0+1, 1);
    MFMAPH(0, 1); BARX();
    LDAH(a0, 1); STAGE_B(0, t0+2, 0);
    MFMAPH(1, 0); BARX();
    STAGE_B(0, t0+2, 1);
    MFMAPH(1, 1);
    waitv<VMC>();
    BARX(); SCHB();
    LDAH(a1, 0); LDBG(b1, 0); STAGE_A(0, t0+2, 0);
    MFMAPH(0, 0); BARX();
    LDBG(b1, 1); STAGE_A(0, t0+2, 1);
    MFMAPH(0, 1); BARX();
    LDAH(a1, 1); STAGE_B(1, t0+3, 0);
    MFMAPH(1, 0); BARX();
    STAGE_B(1, t0+3, 1);
    MFMAPH(1, 1);
    waitv<VMC>();
    BARX(); SCHB();
  }
  {
    const u16 *a0 = As[0], *b0 = Bs[0], *a1 = As[1], *b1 = Bs[1];
    LDAH(a0, 0); LDBG(b0, 0); STAGE_A(1, NT-1, 0);
    MFMAPH(0, 0); BARX();
    LDBG(b0, 1); STAGE_A(1, NT-1, 1);
    MFMAPH(0, 1); BARX();
    LDAH(a0, 1);
    MFMAPH(1, 0); BARX();
    MFMAPH(1, 1);
    waitv<0>();
    BARX(); SCHB();
    LDAH(a1, 0); LDBG(b1, 0);
    MFMAPH(0, 0); BARX();
    LDBG(b1, 1);
    MFMAPH(0, 1); BARX();
    LDAH(a1, 1);
    MFMAPH(1, 0); BARX();
    MFMAPH(1, 1);
  }

#undef STAGE_A
#undef STAGE_B
#undef LDAH
#undef LDBG
#undef CL
#undef BARX
#undef SCHB
#undef MFMAPH

#pragma unroll
  for (int j = 0; j < NF; ++j) {
    int col = n0 + wcol*NF*16 + j*16 + lc;
    float bv = BF16_OUT ? bias[col] : 0.0f;
#pragma unroll
    for (int i = 0; i < MF; ++i) {
      int rowb = m0 + wrow*MF*16 + i*16 + quad*4;
#pragma unroll
      for (int r = 0; r < 4; ++r) {
        float v = acc[i][j][r] + bv;
        if (BF16_OUT) ((u16*)Cout)[(size_t)(rowb+r)*N + col] = f2b(v);
        else          ((float*)Cout)[(size_t)(rowb+r)*N + col] = v;
      }
    }
  }
}

// ---------------- RoPE on K and V (reference ropes V too, not Q) ----------------
__global__ void rope_kernel(const u16* __restrict__ qkv, const float* __restrict__ fc,
                            const float* __restrict__ fs, u16* __restrict__ kout,
                            u16* __restrict__ vout) {
  int tid = threadIdx.x;
  int row = blockIdx.x;             // b*T + t
  int i = tid & 63, kv = tid >> 6;  // pair index, kv head
  int t = row & (T_SEQ-1);
  const u16* p = qkv + (size_t)row*QKVN + EMB + kv*HD + 2*i;
  float ka = b2f(p[0]),   kb = b2f(p[1]);
  float va = b2f(p[KVD]), vb = b2f(p[KVD+1]);
  float c = fc[t*64+i], s = fs[t*64+i];
  size_t ob = (size_t)row*KVD + kv*HD + 2*i;
  kout[ob]   = f2b(ka*c - kb*s);
  kout[ob+1] = f2b(ka*s + kb*c);
  vout[ob]   = f2b(va*c - vb*s);
  vout[ob+1] = f2b(va*s + vb*c);
}

// ---------------- V (b,t,kv,d) -> Vt (b,kv,d,t) ----------------
__global__ void transpose_v_kernel(const u16* __restrict__ vb, u16* __restrict__ vtb) {
  __shared__ u16 tile[32][33];
  int bkv = blockIdx.z;
  int b = bkv >> 2, kv = bkv & 3;
  int d0 = blockIdx.y*32, t0 = blockIdx.x*32;
  int tx = threadIdx.x, ty = threadIdx.y;
#pragma unroll
  for (int i = 0; i < 32; i += 8)
    tile[ty+i][tx] = vb[(size_t)(b*T_SEQ + t0+ty+i)*KVD + kv*HD + d0 + tx];
  __syncthreads();
#pragma unroll
  for (int i = 0; i < 32; i += 8)
    vtb[(size_t)(bkv*HD + d0+ty+i)*T_SEQ + t0 + tx] = tile[tx][ty+i];
}

// ---------------- flash attention v7: v5 structure + conflict-free Ps -------
// One 256-thread block per (b, kv-group, 16-query tile); 4 waves = 4 Q-heads
// sharing staged K/V. v5's double-buffered prefetch-early loop (measured 66.9)
// plus v6's chunk-XOR Ps layout (measured SQ_LDS_BANK_CONFLICT 540K -> 0).
// LDS = 32K(Ks) + 32K(Vs) + 8K(Ps) = 72 KB -> 2 blocks/CU.
__global__ __launch_bounds__(256, 2) void flash_kernel(const u16* __restrict__ qkv,
    const u16* __restrict__ kb, const u16* __restrict__ vtb, u16* __restrict__ yb) {
  __shared__ u16 Ks[2][64*128];          // 2 x 16 KB
  __shared__ u16 Vs[2][128*64];          // 2 x 16 KB
  __shared__ u16 Ps[4][16*64];           // 4 x 2 KB (chunk-XOR swizzled)
  const int tid = threadIdx.x;
  const int w = tid >> 6, lane = tid & 63;
  const int quad = lane >> 4, lc = lane & 15;
  const int bkv = blockIdx.x & 7;        // XCD-pinned (b,kv)
  const int r_  = blockIdx.x >> 3;       // 0..127
  const int b = bkv >> 2, kv = bkv & 3;
  const int h = kv*4 + w;                // wave = one head of the group
  const int qbase = (127 - r_)*16;       // heavy q-tiles dispatch first

  // Q frags (A-layout) for 16 queries of head h; no RoPE on Q
  bf16x8 qf[4];
  {
    const u16* qp = qkv + (size_t)(b*T_SEQ + qbase + lc)*QKVN + h*HD + quad*8;
#pragma unroll
    for (int ks = 0; ks < 4; ++ks) qf[ks] = ld_bf8(qp + ks*32);
  }

  f32x4 o[8] = {};
  float rs[4] = {0.f, 0.f, 0.f, 0.f};
  const u16* kbase = kb  + (size_t)b*T_SEQ*KVD + kv*HD;
  const u16* vbase = vtb + (size_t)bkv*HD*T_SEQ;
  const int nk = qbase + 16;
  const int nt = (nk + 63) >> 6;
  const float cs = 0.08838834764831845f * 1.4426950408889634f;  // scale * log2(e)
  u16* pw = Ps[w];

  // fixed per-thread staging source pointers (source-side XOR swizzle)
  const u16* kptr[4];
  const u16* vptr[4];
#pragma unroll
  for (int rr = 0; rr < 4; ++rr) {
    int krow = (rr*4 + w)*4 + (lane >> 4);
    int kcc  = (lane & 15) ^ (krow & 15);
    kptr[rr] = kbase + (size_t)krow*KVD + kcc*8;
    int vrow = (rr*4 + w)*8 + (lane >> 3);
    int vcc  = (lane & 7) ^ (vrow & 7);
    vptr[rr] = vbase + (size_t)vrow*T_SEQ + vcc*8;
  }

  // per-lane swizzled chunk offsets (hoisted out of the K-loop)
  int koff[4], voff[2], poff[2];
#pragma unroll
  for (int ks = 0; ks < 4; ++ks) koff[ks] = lc*128 + (((ks*4 + quad) ^ lc)*8);
#pragma unroll
  for (int ks = 0; ks < 2; ++ks) voff[ks] = lc*64 + (((ks*4 + quad) ^ (lc & 7))*8);
#pragma unroll
  for (int ks = 0; ks < 2; ++ks) poff[ks] = lc*64 + (((ks*4 + quad) ^ (lc & 7))*8);
  // P-write: row = quad*4+r, u16 addr = row*64 + ((nt2*2+(lc>>3))^(row&7))*8 + (lc&7)
  int pwb[4], pwx[4];
#pragma unroll
  for (int r = 0; r < 4; ++r) {
    pwb[r] = (quad*4 + r)*64 + (lc & 7);
    pwx[r] = (quad*4 + r) & 7;
  }
  const int pcc = lc >> 3;

  // prologue: stage tile 0 -> buf 0, publish
#pragma unroll
  for (int rr = 0; rr < 4; ++rr) glds16(kptr[rr], &Ks[0][(rr*4 + w)*512]);
#pragma unroll
  for (int rr = 0; rr < 4; ++rr) glds16(vptr[rr], &Vs[0][(rr*4 + w)*512]);
  asm volatile("s_waitcnt vmcnt(0)" ::: "memory");
  __builtin_amdgcn_sched_barrier(0);
  __builtin_amdgcn_s_barrier();
  __builtin_amdgcn_sched_barrier(0);

  for (int t = 0; t < nt; ++t) {
    const int cur = t & 1;
    // prefetch tile t+1 into the other buffer (protected by barrier(end t-1))
    if (t + 1 < nt) {
#pragma unroll
      for (int rr = 0; rr < 4; ++rr)
        glds16(kptr[rr] + (size_t)(t+1)*64*KVD, &Ks[cur^1][(rr*4 + w)*512]);
#pragma unroll
      for (int rr = 0; rr < 4; ++rr)
        glds16(vptr[rr] + (size_t)(t+1)*64,     &Vs[cur^1][(rr*4 + w)*512]);
    }
    const u16* ksb = Ks[cur];
    const u16* vsb = Vs[cur];
    const int k0 = t*64;

    // S = Q K^T : 16 queries x 64 keys
    f32x4 sc[4] = {};
    __builtin_amdgcn_s_setprio(1);
#pragma unroll
    for (int nt2 = 0; nt2 < 4; ++nt2)
#pragma unroll
      for (int ks = 0; ks < 4; ++ks) {
        bf16x8 kf = ld_bf8(ksb + nt2*16*128 + koff[ks]);
        sc[nt2] = __builtin_amdgcn_mfma_f32_16x16x32_bf16(qf[ks], kf, sc[nt2], 0, 0, 0);
      }
    __builtin_amdgcn_s_setprio(0);

    // softmax (m=0): p = exp2(s*cs); mask only on diagonal/partial tiles
    if (k0 + 63 > qbase) {
#pragma unroll
      for (int nt2 = 0; nt2 < 4; ++nt2) {
        int key = k0 + nt2*16 + lc;
        int qrow = qbase + quad*4;
#pragma unroll
        for (int r = 0; r < 4; ++r) {
          float e = __builtin_amdgcn_exp2f(sc[nt2][r]*cs);
          float p = (key <= qrow + r) ? e : 0.0f;
          rs[r] += p;
          pw[pwb[r] + ((nt2*2 + pcc) ^ pwx[r])*8] = f2b(p);
        }
      }
    } else {
#pragma unroll
      for (int nt2 = 0; nt2 < 4; ++nt2)
#pragma unroll
        for (int r = 0; r < 4; ++r) {
          float p = __builtin_amdgcn_exp2f(sc[nt2][r]*cs);
          rs[r] += p;
          pw[pwb[r] + ((nt2*2 + pcc) ^ pwx[r])*8] = f2b(p);
        }
    }

    // P: C-layout -> A-layout via per-wave LDS roundtrip (intra-wave DS in-order)
    bf16x8 pa[2];
#pragma unroll
    for (int ks = 0; ks < 2; ++ks)
      pa[ks] = ld_bf8(pw + poff[ks]);

    // O += P V
    __builtin_amdgcn_s_setprio(1);
#pragma unroll
    for (int j = 0; j < 8; ++j)
#pragma unroll
      for (int ks = 0; ks < 2; ++ks) {
        bf16x8 vf = ld_bf8(vsb + j*16*64 + voff[ks]);
        o[j] = __builtin_amdgcn_mfma_f32_16x16x32_bf16(pa[ks], vf, o[j], 0, 0, 0);
      }
    __builtin_amdgcn_s_setprio(0);

    // publish prefetched tile: own loads drained, then block-wide sync
    asm volatile("s_waitcnt vmcnt(0)" ::: "memory");
    __builtin_amdgcn_sched_barrier(0);
    __builtin_amdgcn_s_barrier();
    __builtin_amdgcn_sched_barrier(0);
  }

  // epilogue: l-reduce over the 16 key-lanes, normalize, store
#pragma unroll
  for (int r = 0; r < 4; ++r) {
    float v = rs[r];
#pragma unroll
    for (int off2 = 8; off2 >= 1; off2 >>= 1)
      v += __shfl_xor(v, off2);
    float inv = 1.0f / v;
    size_t orow = (size_t)(b*T_SEQ + qbase + quad*4 + r)*EMB + h*HD;
#pragma unroll
    for (int j = 0; j < 8; ++j)
      yb[orow + j*16 + lc] = f2b(o[j][r]*inv);
  }
}

extern "C" void kernel_launch(void* const* d_in, const int* in_sizes, int n_in,
                              void* d_out, int out_size, void* d_ws, size_t ws_size,
                              hipStream_t stream) {
  const float* x      = (const float*)d_in[0];
  const float* W_attn = (const float*)d_in[1];
  const float* b_attn = (const float*)d_in[2];
  const float* W_proj = (const float*)d_in[3];
  const float* fc     = (const float*)d_in[4];
  const float* fs     = (const float*)d_in[5];

  u16* ws   = (u16*)d_ws;
  u16* xb   = ws;                          // 8.39M elems  (later aliased by yb)
  u16* WaT  = xb   + (size_t)MROWS*EMB;    // 6.29M        (later aliased by WpT)
  u16* qkv  = WaT  + (size_t)QKVN*EMB;     // 12.58M
  u16* kbuf = qkv  + (size_t)MROWS*QKVN;   // 2.10M
  u16* vb   = kbuf + (size_t)MROWS*KVD;    // 2.10M
  u16* vtb  = vb   + (size_t)MROWS*KVD;    // 2.10M  -> total 67.1 MB
  u16* WpT  = WaT;   // W_attn^T dead after gemm1
  u16* yb   = xb;    // x_bf16 dead after gemm1
  float* out = (float*)d_out;

  cvt_x_kernel<<<(MROWS*EMB/4 + 255)/256, 256, 0, stream>>>(
      (const float4*)x, (ushort4*)xb, MROWS*EMB/4);
  transpose_w_kernel<<<dim3(QKVN/64, EMB/64), dim3(16, 16), 0, stream>>>(
      W_attn, WaT, EMB, QKVN);
  // gemm1: 256x192 tiles -> 16x16 = 256 blocks (1/CU)
  gemm_kernel<192, 4, 8, 3, 2, 3, 2, 3, true>
      <<<dim3(QKVN/192, MROWS/256), 512, 0, stream>>>(
      xb, WaT, b_attn, qkv, MROWS, QKVN, EMB);
  rope_kernel<<<MROWS, 256, 0, stream>>>(qkv, fc, fs, kbuf, vb);
  transpose_v_kernel<<<dim3(T_SEQ/32, HD/32, B_SZ*NKV), dim3(32, 8), 0, stream>>>(vb, vtb);
  transpose_w_kernel<<<dim3(EMB/64, EMB/64), dim3(16, 16), 0, stream>>>(
      W_proj, WpT, EMB, EMB);
  // flash v7: 1024 blocks (2/CU), 256 threads = 4 waves = 4 heads
  flash_kernel<<<dim3(B_SZ*NKV*(T_SEQ/16)), 256, 0, stream>>>(qkv, kbuf, vtb, yb);
  // gemm2: 256x128 tiles -> 16x16 = 256 blocks (1/CU)
  gemm_kernel<128, 2, 4, 4, 2, 2, 1, 2, false>
      <<<dim3(EMB/128, MROWS/256), 512, 0, stream>>>(
      yb, WpT, nullptr, out, MROWS, EMB, EMB);
}

// Round 6
// 279.683 us; speedup vs baseline: 1.0257x; 1.0121x over previous
//
#include <hip/hip_runtime.h>
#include <cstdint>
#include <cstddef>

#define T_SEQ 2048
#define B_SZ  2
#define EMB   2048
#define NH    16
#define NKV   4
#define HD    128
#define KVD   512
#define QKVN  3072
#define MROWS (B_SZ*T_SEQ)

typedef __bf16 bf16x8 __attribute__((ext_vector_type(8)));
typedef float  f32x4  __attribute__((ext_vector_type(4)));
typedef short  s16x8  __attribute__((ext_vector_type(8)));
typedef unsigned short u16;

__device__ __forceinline__ u16 f2b(float f) {
  uint32_t u = __builtin_bit_cast(uint32_t, f);
  u += 0x7fffu + ((u >> 16) & 1u);      // RNE
  return (u16)(u >> 16);
}
__device__ __forceinline__ float b2f(u16 h) {
  return __builtin_bit_cast(float, (uint32_t)h << 16);
}
__device__ __forceinline__ bf16x8 ld_bf8(const u16* p) {
  return __builtin_bit_cast(bf16x8, *(const s16x8*)p);
}
__device__ __forceinline__ void glds16(const void* g, void* l) {
  __builtin_amdgcn_global_load_lds((const __attribute__((address_space(1))) void*)g,
                                   (__attribute__((address_space(3))) void*)l, 16, 0, 0);
}
template<int N> __device__ __forceinline__ void waitv() {
  if constexpr (N == 0) asm volatile("s_waitcnt vmcnt(0)" ::: "memory");
  else if constexpr (N == 2) asm volatile("s_waitcnt vmcnt(2)" ::: "memory");
  else if constexpr (N == 3) asm volatile("s_waitcnt vmcnt(3)" ::: "memory");
  __builtin_amdgcn_sched_barrier(0);
}

// ---------------- fp32 -> bf16 elementwise ----------------
__global__ void cvt_x_kernel(const float4* __restrict__ x, ushort4* __restrict__ xb, int n4) {
  int i = blockIdx.x*blockDim.x + threadIdx.x;
  if (i >= n4) return;
  float4 v = x[i];
  ushort4 o;
  o.x = f2b(v.x); o.y = f2b(v.y); o.z = f2b(v.z); o.w = f2b(v.w);
  xb[i] = o;
}

// ---------------- fp32 (R x C) -> bf16 transposed (C x R), vectorized -------
__global__ void transpose_w_kernel(const float* __restrict__ in, u16* __restrict__ out,
                                   int R, int C) {
  __shared__ float tile[64][65];
  int c0 = blockIdx.x*64, r0 = blockIdx.y*64;
  int tx = threadIdx.x, ty = threadIdx.y;   // 16,16
#pragma unroll
  for (int k = 0; k < 4; ++k) {
    int r = ty + k*16;
    float4 v = *(const float4*)&in[(size_t)(r0+r)*C + c0 + tx*4];
    tile[r][tx*4+0] = v.x; tile[r][tx*4+1] = v.y;
    tile[r][tx*4+2] = v.z; tile[r][tx*4+3] = v.w;
  }
  __syncthreads();
#pragma unroll
  for (int k = 0; k < 4; ++k) {
    int c = ty + k*16;                      // output row = original col
    ushort4 o;
    o.x = f2b(tile[tx*4+0][c]);
    o.y = f2b(tile[tx*4+1][c]);
    o.z = f2b(tile[tx*4+2][c]);
    o.w = f2b(tile[tx*4+3][c]);
    *(ushort4*)&out[(size_t)(c0+c)*R + r0 + tx*4] = o;
  }
}

// ---------------- bf16 GEMM, 256xBN tile, 8-phase counted-vmcnt schedule ----
// (unchanged from r2 — verified: 256 blocks = 1/CU for both instantiations)
template<int BN, int WGN, int MF, int NF, int NF1, int SB, int SB1, int VMC, bool BF16_OUT>
__global__ __launch_bounds__(512, 2) void gemm_kernel(const u16* __restrict__ A,
        const u16* __restrict__ Bt, const float* __restrict__ bias,
        void* __restrict__ Cout, int M, int N, int K) {
  constexpr int MF2 = MF/2;
  __shared__ u16 As[2][256*64];
  __shared__ u16 Bs[2][BN*64];
  const int tid = threadIdx.x;
  const int w = tid >> 6, lane = tid & 63;
  const int quad = lane >> 4, lc = lane & 15;
  const int wrow = w / WGN, wcol = w % WGN;
  const int gx = gridDim.x;
  const int lin = blockIdx.y*gx + blockIdx.x;
  const int swz = (lin & 7)*32 + (lin >> 3);
  const int m0 = (swz / gx)*256, n0 = (swz % gx)*BN;

  f32x4 acc[MF][NF] = {};
  bf16x8 af[MF2][2], bfv[NF][2];

  int xoff[2];
#pragma unroll
  for (int ks = 0; ks < 2; ++ks) xoff[ks] = ((ks*4 + quad) ^ (lc & 7))*8;
  const int arow0 = (wrow*MF*16 + lc)*64;
  const int brow0 = (wcol*NF*16 + lc)*64;

  const int srb  = tid >> 3;
  const int spos = (tid & 7) ^ (srb & 7);
  const u16* sAp = A  + (size_t)(m0 + srb)*K + spos*8;
  const u16* sBp = Bt + (size_t)(n0 + srb)*K + spos*8;

#define STAGE_A(bf_, t_, h_) do { \
    glds16(sAp + (size_t)((h_)*2  )*64*K + (size_t)(t_)*64, &As[bf_][((h_)*2  )*4096 + w*512]); \
    glds16(sAp + (size_t)((h_)*2+1)*64*K + (size_t)(t_)*64, &As[bf_][((h_)*2+1)*4096 + w*512]); \
  } while (0)
#define STAGE_B(bf_, t_, p_) do { \
    _Pragma("unroll") for (int r = (p_) ? SB1 : 0; r < ((p_) ? SB : SB1); ++r) \
      glds16(sBp + (size_t)r*64*K + (size_t)(t_)*64, &Bs[bf_][r*4096 + w*512]); \
  } while (0)
#define LDAH(S_, h_) do { _Pragma("unroll") for (int i = 0; i < MF2; ++i) { \
    af[i][0] = ld_bf8((S_) + arow0 + ((h_)*MF2 + i)*1024 + xoff[0]); \
    af[i][1] = ld_bf8((S_) + arow0 + ((h_)*MF2 + i)*1024 + xoff[1]); } } while (0)
#define LDBG(S_, g_) do { _Pragma("unroll") for (int j = (g_) ? NF1 : 0; j < ((g_) ? NF : NF1); ++j) { \
    bfv[j][0] = ld_bf8((S_) + brow0 + j*1024 + xoff[0]); \
    bfv[j][1] = ld_bf8((S_) + brow0 + j*1024 + xoff[1]); } } while (0)
#define CL(h_, g_) do { _Pragma("unroll") for (int ks = 0; ks < 2; ++ks) \
    _Pragma("unroll") for (int i = 0; i < MF2; ++i) \
    _Pragma("unroll") for (int j = (g_) ? NF1 : 0; j < ((g_) ? NF : NF1); ++j) \
      acc[(h_)*MF2+i][j] = __builtin_amdgcn_mfma_f32_16x16x32_bf16( \
          af[i][ks], bfv[j][ks], acc[(h_)*MF2+i][j], 0, 0, 0); } while (0)
#define BARX()  __builtin_amdgcn_s_barrier()
#define SCHB()  __builtin_amdgcn_sched_barrier(0)
#define MFMAPH(h_, g_) do { BARX(); \
    asm volatile("s_waitcnt lgkmcnt(0)" ::: "memory"); SCHB(); \
    __builtin_amdgcn_s_setprio(1); CL(h_, g_); __builtin_amdgcn_s_setprio(0); \
  } while (0)

  const int NT = K >> 6;
  STAGE_B(0, 0, 0); STAGE_B(0, 0, 1);
  STAGE_A(0, 0, 0); STAGE_A(0, 0, 1);
  STAGE_B(1, 1, 0); STAGE_B(1, 1, 1);
  waitv<VMC>();
  BARX(); SCHB();

  for (int t0 = 0; t0 < NT-2; t0 += 2) {
    const u16 *a0 = As[0], *b0 = Bs[0], *a1 = As[1], *b1 = Bs[1];
    LDAH(a0, 0); LDBG(b0, 0); STAGE_A(1, t0+1, 0);
    MFMAPH(0, 0); BARX();
    LDBG(b0, 1); STAGE_A(1, t0+1, 1);
    MFMAPH(0, 1); BARX();
    LDAH(a0, 1); STAGE_B(0, t0+2, 0);
    MFMAPH(1, 0); BARX();
    STAGE_B(0, t0+2, 1);
    MFMAPH(1, 1);
    waitv<VMC>();
    BARX(); SCHB();
    LDAH(a1, 0); LDBG(b1, 0); STAGE_A(0, t0+2, 0);
    MFMAPH(0, 0); BARX();
    LDBG(b1, 1); STAGE_A(0, t0+2, 1);
    MFMAPH(0, 1); BARX();
    LDAH(a1, 1); STAGE_B(1, t0+3, 0);
    MFMAPH(1, 0); BARX();
    STAGE_B(1, t0+3, 1);
    MFMAPH(1, 1);
    waitv<VMC>();
    BARX(); SCHB();
  }
  {
    const u16 *a0 = As[0], *b0 = Bs[0], *a1 = As[1], *b1 = Bs[1];
    LDAH(a0, 0); LDBG(b0, 0); STAGE_A(1, NT-1, 0);
    MFMAPH(0, 0); BARX();
    LDBG(b0, 1); STAGE_A(1, NT-1, 1);
    MFMAPH(0, 1); BARX();
    LDAH(a0, 1);
    MFMAPH(1, 0); BARX();
    MFMAPH(1, 1);
    waitv<0>();
    BARX(); SCHB();
    LDAH(a1, 0); LDBG(b1, 0);
    MFMAPH(0, 0); BARX();
    LDBG(b1, 1);
    MFMAPH(0, 1); BARX();
    LDAH(a1, 1);
    MFMAPH(1, 0); BARX();
    MFMAPH(1, 1);
  }

#undef STAGE_A
#undef STAGE_B
#undef LDAH
#undef LDBG
#undef CL
#undef BARX
#undef SCHB
#undef MFMAPH

#pragma unroll
  for (int j = 0; j < NF; ++j) {
    int col = n0 + wcol*NF*16 + j*16 + lc;
    float bv = BF16_OUT ? bias[col] : 0.0f;
#pragma unroll
    for (int i = 0; i < MF; ++i) {
      int rowb = m0 + wrow*MF*16 + i*16 + quad*4;
#pragma unroll
      for (int r = 0; r < 4; ++r) {
        float v = acc[i][j][r] + bv;
        if (BF16_OUT) ((u16*)Cout)[(size_t)(rowb+r)*N + col] = f2b(v);
        else          ((float*)Cout)[(size_t)(rowb+r)*N + col] = v;
      }
    }
  }
}

// ---------------- RoPE on K and V (reference ropes V too, not Q) ----------------
__global__ void rope_kernel(const u16* __restrict__ qkv, const float* __restrict__ fc,
                            const float* __restrict__ fs, u16* __restrict__ kout,
                            u16* __restrict__ vout) {
  int tid = threadIdx.x;
  int row = blockIdx.x;             // b*T + t
  int i = tid & 63, kv = tid >> 6;  // pair index, kv head
  int t = row & (T_SEQ-1);
  const u16* p = qkv + (size_t)row*QKVN + EMB + kv*HD + 2*i;
  float ka = b2f(p[0]),   kb = b2f(p[1]);
  float va = b2f(p[KVD]), vb = b2f(p[KVD+1]);
  float c = fc[t*64+i], s = fs[t*64+i];
  size_t ob = (size_t)row*KVD + kv*HD + 2*i;
  kout[ob]   = f2b(ka*c - kb*s);
  kout[ob+1] = f2b(ka*s + kb*c);
  vout[ob]   = f2b(va*c - vb*s);
  vout[ob+1] = f2b(va*s + vb*c);
}

// ---------------- V (b,t,kv,d) -> Vt (b,kv,d,t) ----------------
__global__ void transpose_v_kernel(const u16* __restrict__ vb, u16* __restrict__ vtb) {
  __shared__ u16 tile[32][33];
  int bkv = blockIdx.z;
  int b = bkv >> 2, kv = bkv & 3;
  int d0 = blockIdx.y*32, t0 = blockIdx.x*32;
  int tx = threadIdx.x, ty = threadIdx.y;
#pragma unroll
  for (int i = 0; i < 32; i += 8)
    tile[ty+i][tx] = vb[(size_t)(b*T_SEQ + t0+ty+i)*KVD + kv*HD + d0 + tx];
  __syncthreads();
#pragma unroll
  for (int i = 0; i < 32; i += 8)
    vtb[(size_t)(bkv*HD + d0+ty+i)*T_SEQ + t0 + tx] = tile[tx][ty+i];
}

// ---------------- flash attention v8: 32 queries/wave (wrapped pair) --------
// One 256-thread block per (b, kv-group, {light,heavy} q-tile pair); 4 waves =
// 4 Q-heads sharing staged K/V. Each wave owns sub-tile A = q-tile r_ (bottom)
// and B = q-tile 127-r_ (top): ntA+ntB ~= const 33 -> all 512 blocks resident
// at 2/CU, no tail imbalance. K/V frags ds_read ONCE, feed both sub-tiles' MFMA
// chains (2x ILP, 2x reuse per staged byte; staging+barriers per query halve).
// P roundtrip through the single 2KB/wave Ps: B-write -> B-read -> A-write ->
// A-read (intra-wave DS in-order; may-alias keeps compiler order). LDS 72 KB.
__global__ __launch_bounds__(256, 2) void flash_kernel(const u16* __restrict__ qkv,
    const u16* __restrict__ kb, const u16* __restrict__ vtb, u16* __restrict__ yb) {
  __shared__ u16 Ks[2][64*128];          // 2 x 16 KB
  __shared__ u16 Vs[2][128*64];          // 2 x 16 KB
  __shared__ u16 Ps[4][16*64];           // 4 x 2 KB (chunk-XOR swizzled)
  const int tid = threadIdx.x;
  const int w = tid >> 6, lane = tid & 63;
  const int quad = lane >> 4, lc = lane & 15;
  const int bkv = blockIdx.x & 7;        // XCD-pinned (b,kv)
  const int r_  = blockIdx.x >> 3;       // 0..63
  const int b = bkv >> 2, kv = bkv & 3;
  const int h = kv*4 + w;                // wave = one head of the group
  const int qbA = r_*16;                 // light sub-tile (bottom of triangle)
  const int qbB = (127 - r_)*16;         // heavy sub-tile (top)

  // Q frags (A-layout) for both sub-tiles; no RoPE on Q
  bf16x8 qfA[4], qfB[4];
  {
    const u16* qpA = qkv + (size_t)(b*T_SEQ + qbA + lc)*QKVN + h*HD + quad*8;
    const u16* qpB = qkv + (size_t)(b*T_SEQ + qbB + lc)*QKVN + h*HD + quad*8;
#pragma unroll
    for (int ks = 0; ks < 4; ++ks) { qfA[ks] = ld_bf8(qpA + ks*32); qfB[ks] = ld_bf8(qpB + ks*32); }
  }

  f32x4 oA[8] = {}, oB[8] = {};
  float rsA[4] = {0.f,0.f,0.f,0.f}, rsB[4] = {0.f,0.f,0.f,0.f};
  const u16* kbase = kb  + (size_t)b*T_SEQ*KVD + kv*HD;
  const u16* vbase = vtb + (size_t)bkv*HD*T_SEQ;
  const int ntA = (qbA + 16 + 63) >> 6;  // A's causal tile count
  const int nt  = (qbB + 16 + 63) >> 6;  // loop bound (B's count)
  const float cs = 0.08838834764831845f * 1.4426950408889634f;  // scale*log2(e)
  u16* pw = Ps[w];

  // fixed per-thread staging source pointers (source-side XOR swizzle)
  const u16* kptr[4];
  const u16* vptr[4];
#pragma unroll
  for (int rr = 0; rr < 4; ++rr) {
    int krow = (rr*4 + w)*4 + (lane >> 4);
    int kcc  = (lane & 15) ^ (krow & 15);
    kptr[rr] = kbase + (size_t)krow*KVD + kcc*8;
    int vrow = (rr*4 + w)*8 + (lane >> 3);
    int vcc  = (lane & 7) ^ (vrow & 7);
    vptr[rr] = vbase + (size_t)vrow*T_SEQ + vcc*8;
  }

  // per-lane swizzled chunk offsets
  int koff[4], voff[2], poff[2];
#pragma unroll
  for (int ks = 0; ks < 4; ++ks) koff[ks] = lc*128 + (((ks*4 + quad) ^ lc)*8);
#pragma unroll
  for (int ks = 0; ks < 2; ++ks) voff[ks] = lc*64 + (((ks*4 + quad) ^ (lc & 7))*8);
#pragma unroll
  for (int ks = 0; ks < 2; ++ks) poff[ks] = lc*64 + (((ks*4 + quad) ^ (lc & 7))*8);
  // P-write: row = quad*4+r, u16 addr = row*64 + ((nt2*2+(lc>>3))^(row&7))*8 + (lc&7)
  int pwb[4], pwx[4];
#pragma unroll
  for (int r = 0; r < 4; ++r) {
    pwb[r] = (quad*4 + r)*64 + (lc & 7);
    pwx[r] = (quad*4 + r) & 7;
  }
  const int pcc = lc >> 3;

  // prologue: stage tile 0 -> buf 0, publish
#pragma unroll
  for (int rr = 0; rr < 4; ++rr) glds16(kptr[rr], &Ks[0][(rr*4 + w)*512]);
#pragma unroll
  for (int rr = 0; rr < 4; ++rr) glds16(vptr[rr], &Vs[0][(rr*4 + w)*512]);
  asm volatile("s_waitcnt vmcnt(0)" ::: "memory");
  __builtin_amdgcn_sched_barrier(0);
  __builtin_amdgcn_s_barrier();
  __builtin_amdgcn_sched_barrier(0);

// softmax for one sub-tile: sc -> P(LDS) + rs accumulate
#define SMAX(SC_, QB_, RS_) do { \
    if (k0 + 63 > (QB_)) { \
      _Pragma("unroll") for (int nt2 = 0; nt2 < 4; ++nt2) { \
        int key = k0 + nt2*16 + lc; \
        int qrow = (QB_) + quad*4; \
        _Pragma("unroll") for (int r = 0; r < 4; ++r) { \
          float e = __builtin_amdgcn_exp2f(SC_[nt2][r]*cs); \
          float p = (key <= qrow + r) ? e : 0.0f; \
          RS_[r] += p; \
          pw[pwb[r] + ((nt2*2 + pcc) ^ pwx[r])*8] = f2b(p); \
        } \
      } \
    } else { \
      _Pragma("unroll") for (int nt2 = 0; nt2 < 4; ++nt2) \
        _Pragma("unroll") for (int r = 0; r < 4; ++r) { \
          float p = __builtin_amdgcn_exp2f(SC_[nt2][r]*cs); \
          RS_[r] += p; \
          pw[pwb[r] + ((nt2*2 + pcc) ^ pwx[r])*8] = f2b(p); \
        } \
    } \
  } while (0)

// one K/V tile for sub-tile B (always) + A (when DOA_): K/V frags read once
#define TILE_BODY(DOA_) do { \
    f32x4 scB[4] = {}; f32x4 scA[4] = {}; \
    __builtin_amdgcn_s_setprio(1); \
    _Pragma("unroll") for (int nt2 = 0; nt2 < 4; ++nt2) { \
      bf16x8 kf[4]; \
      _Pragma("unroll") for (int ks = 0; ks < 4; ++ks) \
        kf[ks] = ld_bf8(ksb + nt2*16*128 + koff[ks]); \
      _Pragma("unroll") for (int ks = 0; ks < 4; ++ks) { \
        scB[nt2] = __builtin_amdgcn_mfma_f32_16x16x32_bf16(qfB[ks], kf[ks], scB[nt2], 0, 0, 0); \
        if (DOA_) scA[nt2] = __builtin_amdgcn_mfma_f32_16x16x32_bf16(qfA[ks], kf[ks], scA[nt2], 0, 0, 0); \
      } \
    } \
    __builtin_amdgcn_s_setprio(0); \
    SMAX(scB, qbB, rsB); \
    bf16x8 paB[2]; \
    _Pragma("unroll") for (int ks = 0; ks < 2; ++ks) paB[ks] = ld_bf8(pw + poff[ks]); \
    bf16x8 paA[2]; \
    if (DOA_) { \
      SMAX(scA, qbA, rsA); \
      _Pragma("unroll") for (int ks = 0; ks < 2; ++ks) paA[ks] = ld_bf8(pw + poff[ks]); \
    } \
    __builtin_amdgcn_s_setprio(1); \
    _Pragma("unroll") for (int j = 0; j < 8; ++j) { \
      bf16x8 vf0 = ld_bf8(vsb + j*16*64 + voff[0]); \
      bf16x8 vf1 = ld_bf8(vsb + j*16*64 + voff[1]); \
      oB[j] = __builtin_amdgcn_mfma_f32_16x16x32_bf16(paB[0], vf0, oB[j], 0, 0, 0); \
      oB[j] = __builtin_amdgcn_mfma_f32_16x16x32_bf16(paB[1], vf1, oB[j], 0, 0, 0); \
      if (DOA_) { \
        oA[j] = __builtin_amdgcn_mfma_f32_16x16x32_bf16(paA[0], vf0, oA[j], 0, 0, 0); \
        oA[j] = __builtin_amdgcn_mfma_f32_16x16x32_bf16(paA[1], vf1, oA[j], 0, 0, 0); \
      } \
    } \
    __builtin_amdgcn_s_setprio(0); \
  } while (0)

  for (int t = 0; t < nt; ++t) {
    const int cur = t & 1;
    // prefetch tile t+1 into the other buffer (protected by barrier(end t-1))
    if (t + 1 < nt) {
#pragma unroll
      for (int rr = 0; rr < 4; ++rr)
        glds16(kptr[rr] + (size_t)(t+1)*64*KVD, &Ks[cur^1][(rr*4 + w)*512]);
#pragma unroll
      for (int rr = 0; rr < 4; ++rr)
        glds16(vptr[rr] + (size_t)(t+1)*64,     &Vs[cur^1][(rr*4 + w)*512]);
    }
    const u16* ksb = Ks[cur];
    const u16* vsb = Vs[cur];
    const int k0 = t*64;

    if (t < ntA) { TILE_BODY(1); } else { TILE_BODY(0); }

    // publish prefetched tile: own loads drained, then block-wide sync
    asm volatile("s_waitcnt vmcnt(0)" ::: "memory");
    __builtin_amdgcn_sched_barrier(0);
    __builtin_amdgcn_s_barrier();
    __builtin_amdgcn_sched_barrier(0);
  }
#undef TILE_BODY
#undef SMAX

  // epilogue: l-reduce over the 16 key-lanes, normalize, store (both sub-tiles)
#pragma unroll
  for (int r = 0; r < 4; ++r) {
    float vA = rsA[r], vB = rsB[r];
#pragma unroll
    for (int off2 = 8; off2 >= 1; off2 >>= 1) {
      vA += __shfl_xor(vA, off2);
      vB += __shfl_xor(vB, off2);
    }
    float invA = 1.0f / vA, invB = 1.0f / vB;
    size_t orowA = (size_t)(b*T_SEQ + qbA + quad*4 + r)*EMB + h*HD;
    size_t orowB = (size_t)(b*T_SEQ + qbB + quad*4 + r)*EMB + h*HD;
#pragma unroll
    for (int j = 0; j < 8; ++j) {
      yb[orowA + j*16 + lc] = f2b(oA[j][r]*invA);
      yb[orowB + j*16 + lc] = f2b(oB[j][r]*invB);
    }
  }
}

extern "C" void kernel_launch(void* const* d_in, const int* in_sizes, int n_in,
                              void* d_out, int out_size, void* d_ws, size_t ws_size,
                              hipStream_t stream) {
  const float* x      = (const float*)d_in[0];
  const float* W_attn = (const float*)d_in[1];
  const float* b_attn = (const float*)d_in[2];
  const float* W_proj = (const float*)d_in[3];
  const float* fc     = (const float*)d_in[4];
  const float* fs     = (const float*)d_in[5];

  u16* ws   = (u16*)d_ws;
  u16* xb   = ws;                          // 8.39M elems  (later aliased by yb)
  u16* WaT  = xb   + (size_t)MROWS*EMB;    // 6.29M        (later aliased by WpT)
  u16* qkv  = WaT  + (size_t)QKVN*EMB;     // 12.58M
  u16* kbuf = qkv  + (size_t)MROWS*QKVN;   // 2.10M
  u16* vb   = kbuf + (size_t)MROWS*KVD;    // 2.10M
  u16* vtb  = vb   + (size_t)MROWS*KVD;    // 2.10M  -> total 67.1 MB
  u16* WpT  = WaT;   // W_attn^T dead after gemm1
  u16* yb   = xb;    // x_bf16 dead after gemm1
  float* out = (float*)d_out;

  cvt_x_kernel<<<(MROWS*EMB/4 + 255)/256, 256, 0, stream>>>(
      (const float4*)x, (ushort4*)xb, MROWS*EMB/4);
  transpose_w_kernel<<<dim3(QKVN/64, EMB/64), dim3(16, 16), 0, stream>>>(
      W_attn, WaT, EMB, QKVN);
  // gemm1: 256x192 tiles -> 16x16 = 256 blocks (1/CU)
  gemm_kernel<192, 4, 8, 3, 2, 3, 2, 3, true>
      <<<dim3(QKVN/192, MROWS/256), 512, 0, stream>>>(
      xb, WaT, b_attn, qkv, MROWS, QKVN, EMB);
  rope_kernel<<<MROWS, 256, 0, stream>>>(qkv, fc, fs, kbuf, vb);
  transpose_v_kernel<<<dim3(T_SEQ/32, HD/32, B_SZ*NKV), dim3(32, 8), 0, stream>>>(vb, vtb);
  transpose_w_kernel<<<dim3(EMB/64, EMB/64), dim3(16, 16), 0, stream>>>(
      W_proj, WpT, EMB, EMB);
  // flash v8: 512 blocks (all resident, 2/CU), 256 threads = 4 waves = 4 heads,
  // each wave = wrapped q-tile pair {r_, 127-r_}
  flash_kernel<<<dim3(B_SZ*NKV*(T_SEQ/32)), 256, 0, stream>>>(qkv, kbuf, vtb, yb);
  // gemm2: 256x128 tiles -> 16x16 = 256 blocks (1/CU)
  gemm_kernel<128, 2, 4, 4, 2, 2, 1, 2, false>
      <<<dim3(EMB/128, MROWS/256), 512, 0, stream>>>(
      yb, WpT, nullptr, out, MROWS, EMB, EMB);
}